// Round 5
// baseline (303.830 us; speedup 1.0000x reference)
//
#include <hip/hip_runtime.h>
#include <hip/hip_bf16.h>
#include <cstdint>
#include <cstddef>

#define D 768
#define BATCH 8
#define LC 2048
#define LQ 1024
#define SCALE 0.03608439182435161f /* 1/sqrt(768) */

typedef __attribute__((ext_vector_type(8))) short short8;
typedef __attribute__((ext_vector_type(4))) float floatx4;

__device__ __forceinline__ short f2bf(float f) {
    union { float f; uint32_t u; } v; v.f = f;
    uint32_t r = v.u + 0x7fffu + ((v.u >> 16) & 1u);
    return (short)(r >> 16);
}

// ---- async global->LDS, 16B per lane ----
__device__ __forceinline__ void gl_lds16(const short* g, short* l) {
    __builtin_amdgcn_global_load_lds(
        reinterpret_cast<const __attribute__((address_space(1))) unsigned int*>(
            reinterpret_cast<uintptr_t>(g)),
        reinterpret_cast<__attribute__((address_space(3))) unsigned int*>(
            reinterpret_cast<uintptr_t>(l)),
        16, 0, 0);
}

// stage a 128x32 bf16 tile into lds[128][32]
__device__ __forceinline__ void stage_tile(const short* gbase, int ld, int m0, int k0,
                                           short* lds, int tid) {
    const int r = tid >> 2, kc = (tid & 3) * 8;
    gl_lds16(gbase + (size_t)(m0 + r) * ld + k0 + kc, lds + tid * 8);
    gl_lds16(gbase + (size_t)(m0 + r + 64) * ld + k0 + kc, lds + 2048 + tid * 8);
}

// m97-structure K-loop: C[128,128] += A[128,K] * B[128,K]^T
__device__ __forceinline__ void mfma_tile_loop(
    const short* Ab, const short* Bb, int lda, int ldb, int K, int m0, int n0,
    short* sA, short* sB, int tid, floatx4 acc[4][4]) {
    const int w = tid >> 6, lane = tid & 63, l15 = lane & 15, quad = lane >> 4;
    const int wm = (w >> 1) * 64, wn = (w & 1) * 64;
    for (int k0 = 0; k0 < K; k0 += 32) {
        stage_tile(Ab, lda, m0, k0, sA, tid);
        stage_tile(Bb, ldb, n0, k0, sB, tid);
        __syncthreads();
        short8 af[4], bf[4];
#pragma unroll
        for (int mt = 0; mt < 4; ++mt)
            af[mt] = *reinterpret_cast<const short8*>(&sA[(wm + mt * 16 + l15) * 32 + quad * 8]);
#pragma unroll
        for (int nt = 0; nt < 4; ++nt)
            bf[nt] = *reinterpret_cast<const short8*>(&sB[(wn + nt * 16 + l15) * 32 + quad * 8]);
#pragma unroll
        for (int mt = 0; mt < 4; ++mt)
#pragma unroll
            for (int nt = 0; nt < 4; ++nt)
                acc[mt][nt] = __builtin_amdgcn_mfma_f32_16x16x32_bf16(af[mt], bf[nt], acc[mt][nt], 0, 0, 0);
        __syncthreads();
    }
}

// ---------------- cast fp32 -> bf16 ----------------
__global__ void cast_bf16_kernel(const float* __restrict__ src, short* __restrict__ dst, int n4) {
    int i = blockIdx.x * 256 + threadIdx.x;
    if (i >= n4) return;
    float4 v = reinterpret_cast<const float4*>(src)[i];
    short4 o;
    o.x = f2bf(v.x); o.y = f2bf(v.y); o.z = f2bf(v.z); o.w = f2bf(v.w);
    reinterpret_cast<short4*>(dst)[i] = o;
}

// ---------------- qh pass: read qh once -> qh_b (bf16 row-major) + qhT (bf16 transposed) ----------------
__global__ void qh_pass_kernel(const float* __restrict__ qh, short* __restrict__ qh_b,
                               short* __restrict__ qhT) {
    __shared__ float tile[32][33];
    const int b = blockIdx.z;
    const int q0 = blockIdx.x * 32, d0 = blockIdx.y * 32;
    const int t = threadIdx.x;
    const int r = t >> 3, c = (t & 7) * 4;
    const float4 v = *reinterpret_cast<const float4*>(qh + ((size_t)b * LQ + q0 + r) * D + d0 + c);
    tile[r][c] = v.x; tile[r][c + 1] = v.y; tile[r][c + 2] = v.z; tile[r][c + 3] = v.w;
    short4 d;
    d.x = f2bf(v.x); d.y = f2bf(v.y); d.z = f2bf(v.z); d.w = f2bf(v.w);
    *reinterpret_cast<short4*>(qh_b + ((size_t)b * LQ + q0 + r) * D + d0 + c) = d;
    __syncthreads();
    short4 o;
    o.x = f2bf(tile[c][r]); o.y = f2bf(tile[c + 1][r]);
    o.z = f2bf(tile[c + 2][r]); o.w = f2bf(tile[c + 3][r]);
    *reinterpret_cast<short4*>(qhT + ((size_t)b * D + d0 + r) * LQ + q0 + c) = o;
}

// ---------------- GEMM1: query = qh_b * W_b^T + bias -> bf16 ----------------
__global__ __launch_bounds__(256, 2) void gemm1_kernel(
    const short* __restrict__ A, const short* __restrict__ W,
    const float* __restrict__ bias, short* __restrict__ Q) {
    __shared__ short sA[128 * 32];
    __shared__ short sB[128 * 32];
    const int m0 = blockIdx.x * 128, n0 = blockIdx.y * 128;
    const int tid = threadIdx.x;
    const int w = tid >> 6, lane = tid & 63, l15 = lane & 15, quad = lane >> 4;
    const int wm = (w >> 1) * 64, wn = (w & 1) * 64;
    floatx4 acc[4][4];
#pragma unroll
    for (int i = 0; i < 4; ++i)
#pragma unroll
        for (int j = 0; j < 4; ++j) { floatx4 z = {0.f, 0.f, 0.f, 0.f}; acc[i][j] = z; }
    mfma_tile_loop(A, W, D, D, D, m0, n0, sA, sB, tid, acc);
    float bv[4];
#pragma unroll
    for (int nt = 0; nt < 4; ++nt) bv[nt] = bias[n0 + wn + nt * 16 + l15];
#pragma unroll
    for (int mt = 0; mt < 4; ++mt)
#pragma unroll
        for (int r = 0; r < 4; ++r) {
            int row = m0 + wm + mt * 16 + quad * 4 + r;
#pragma unroll
            for (int nt = 0; nt < 4; ++nt)
                Q[(size_t)row * D + n0 + wn + nt * 16 + l15] = f2bf(acc[mt][nt][r] + bv[nt]);
        }
}

// ---------------- ctx pass: copy ctx into out[:, :, 0:768] AND cast to bf16 ----------------
__global__ void ctx_pass_kernel(const float* __restrict__ ctx, float* __restrict__ out,
                                short* __restrict__ ctxb) {
    size_t i = (size_t)blockIdx.x * 256 + threadIdx.x;
    size_t row = i / 192;
    size_t c4 = i % 192;
    float4 v = reinterpret_cast<const float4*>(ctx)[i];
    reinterpret_cast<float4*>(out)[row * 384 + c4] = v;
    short4 o;
    o.x = f2bf(v.x); o.y = f2bf(v.y); o.z = f2bf(v.z); o.w = f2bf(v.w);
    reinterpret_cast<short4*>(ctxb)[i] = o;
}

// ---------------- fused scores + masked softmax -> P (bf16, normalized) ----------------
// grid (LC/32, B), 512 threads (8 waves). Block: 32 ctx rows x all 1024 q cols.
// LDS-staged A (32x32) and B (1024x32) per K-step. Wave w owns cols [128w,128w+128).
__global__ __launch_bounds__(512, 4) void scores_fused_kernel(
    const short* __restrict__ ctxb, const short* __restrict__ query_b,
    const int* __restrict__ qmask, short* __restrict__ P) {
    __shared__ short sA[32 * 32];      // 2 KB
    __shared__ short sB[1024 * 32];    // 64 KB
    __shared__ float redM[8][32];
    __shared__ float redS[8][32];
    const int b = blockIdx.y;
    const int c0 = blockIdx.x * 32;
    const int tid = threadIdx.x;
    const int w = tid >> 6, lane = tid & 63, l15 = lane & 15, quad = lane >> 4;
    const int n0 = w * 128;
    const short* Ab = ctxb + ((size_t)b * LC + c0) * D;
    const short* Bb = query_b + (size_t)b * LQ * D;
    const int r = tid >> 2, kc = (tid & 3) * 8;

    floatx4 acc[2][8];
#pragma unroll
    for (int mt = 0; mt < 2; ++mt)
#pragma unroll
        for (int nt = 0; nt < 8; ++nt) { floatx4 z = {0.f, 0.f, 0.f, 0.f}; acc[mt][nt] = z; }

    for (int k0 = 0; k0 < D; k0 += 32) {
        if (tid < 128)
            gl_lds16(Ab + (size_t)r * D + k0 + kc, sA + tid * 8);
#pragma unroll
        for (int seg = 0; seg < 8; ++seg)
            gl_lds16(Bb + (size_t)(seg * 128 + r) * D + k0 + kc, sB + seg * 4096 + tid * 8);
        __syncthreads();
        short8 af[2];
#pragma unroll
        for (int mt = 0; mt < 2; ++mt)
            af[mt] = *reinterpret_cast<const short8*>(&sA[(mt * 16 + l15) * 32 + quad * 8]);
#pragma unroll
        for (int nt = 0; nt < 8; ++nt) {
            short8 bf = *reinterpret_cast<const short8*>(&sB[(n0 + nt * 16 + l15) * 32 + quad * 8]);
            acc[0][nt] = __builtin_amdgcn_mfma_f32_16x16x32_bf16(af[0], bf, acc[0][nt], 0, 0, 0);
            acc[1][nt] = __builtin_amdgcn_mfma_f32_16x16x32_bf16(af[1], bf, acc[1][nt], 0, 0, 0);
        }
        __syncthreads();
    }

    // scale + mask + row max (rows: mt*16 + quad*4 + r_i, wave-local 16-lane groups)
    const int* mk = qmask + b * LQ;
    float pm[2][4];
#pragma unroll
    for (int mt = 0; mt < 2; ++mt)
#pragma unroll
        for (int ri = 0; ri < 4; ++ri) pm[mt][ri] = -1e38f;
#pragma unroll
    for (int nt = 0; nt < 8; ++nt) {
        const bool valid = (mk[n0 + nt * 16 + l15] != 0);
#pragma unroll
        for (int mt = 0; mt < 2; ++mt)
#pragma unroll
            for (int ri = 0; ri < 4; ++ri) {
                float x = valid ? acc[mt][nt][ri] * SCALE : -1e30f;
                acc[mt][nt][ri] = x;
                pm[mt][ri] = fmaxf(pm[mt][ri], x);
            }
    }
#pragma unroll
    for (int off = 1; off < 16; off <<= 1)
#pragma unroll
        for (int mt = 0; mt < 2; ++mt)
#pragma unroll
            for (int ri = 0; ri < 4; ++ri)
                pm[mt][ri] = fmaxf(pm[mt][ri], __shfl_xor(pm[mt][ri], off, 64));
    if (l15 == 0) {
#pragma unroll
        for (int mt = 0; mt < 2; ++mt)
#pragma unroll
            for (int ri = 0; ri < 4; ++ri)
                redM[w][mt * 16 + quad * 4 + ri] = pm[mt][ri];
    }
    __syncthreads();
    float M[2][4];
#pragma unroll
    for (int mt = 0; mt < 2; ++mt)
#pragma unroll
        for (int ri = 0; ri < 4; ++ri) {
            float m = -1e38f;
#pragma unroll
            for (int ww = 0; ww < 8; ++ww) m = fmaxf(m, redM[ww][mt * 16 + quad * 4 + ri]);
            M[mt][ri] = m;
        }
    float ps[2][4] = {{0.f, 0.f, 0.f, 0.f}, {0.f, 0.f, 0.f, 0.f}};
#pragma unroll
    for (int nt = 0; nt < 8; ++nt)
#pragma unroll
        for (int mt = 0; mt < 2; ++mt)
#pragma unroll
            for (int ri = 0; ri < 4; ++ri) {
                float p = __expf(acc[mt][nt][ri] - M[mt][ri]);
                acc[mt][nt][ri] = p;
                ps[mt][ri] += p;
            }
#pragma unroll
    for (int off = 1; off < 16; off <<= 1)
#pragma unroll
        for (int mt = 0; mt < 2; ++mt)
#pragma unroll
            for (int ri = 0; ri < 4; ++ri)
                ps[mt][ri] += __shfl_xor(ps[mt][ri], off, 64);
    if (l15 == 0) {
#pragma unroll
        for (int mt = 0; mt < 2; ++mt)
#pragma unroll
            for (int ri = 0; ri < 4; ++ri)
                redS[w][mt * 16 + quad * 4 + ri] = ps[mt][ri];
    }
    __syncthreads();
    float inv[2][4];
#pragma unroll
    for (int mt = 0; mt < 2; ++mt)
#pragma unroll
        for (int ri = 0; ri < 4; ++ri) {
            float s = 0.f;
#pragma unroll
            for (int ww = 0; ww < 8; ++ww) s += redS[ww][mt * 16 + quad * 4 + ri];
            inv[mt][ri] = 1.0f / s;
        }
    short* Pb = P + ((size_t)b * LC + c0) * LQ;
#pragma unroll
    for (int mt = 0; mt < 2; ++mt)
#pragma unroll
        for (int ri = 0; ri < 4; ++ri) {
            short* prow = Pb + (size_t)(mt * 16 + quad * 4 + ri) * LQ + n0;
#pragma unroll
            for (int nt = 0; nt < 8; ++nt)
                prow[nt * 16 + l15] = f2bf(acc[mt][nt][ri] * inv[mt][ri]);
        }
}

// ---------------- K2: attn_out = P * qhT^T -> fp32 into out[...,768:] ----------------
__global__ __launch_bounds__(256, 2) void gemm2_kernel(
    const short* __restrict__ P, const short* __restrict__ qhT,
    float* __restrict__ out) {
    __shared__ short sA[128 * 32];
    __shared__ short sB[128 * 32];
    const int b = blockIdx.z;
    const int m0 = blockIdx.x * 128, n0 = blockIdx.y * 128;
    const int tid = threadIdx.x;
    const int w = tid >> 6, lane = tid & 63, l15 = lane & 15, quad = lane >> 4;
    const int wm = (w >> 1) * 64, wn = (w & 1) * 64;
    floatx4 acc[4][4];
#pragma unroll
    for (int i = 0; i < 4; ++i)
#pragma unroll
        for (int j = 0; j < 4; ++j) { floatx4 z = {0.f, 0.f, 0.f, 0.f}; acc[i][j] = z; }
    mfma_tile_loop(P + (size_t)b * LC * LQ, qhT + (size_t)b * D * LQ,
                   LQ, LQ, LQ, m0, n0, sA, sB, tid, acc);
#pragma unroll
    for (int mt = 0; mt < 4; ++mt)
#pragma unroll
        for (int r = 0; r < 4; ++r) {
            size_t row = (size_t)b * LC + m0 + wm + mt * 16 + quad * 4 + r;
#pragma unroll
            for (int nt = 0; nt < 4; ++nt)
                out[row * 1536 + 768 + n0 + wn + nt * 16 + l15] = acc[mt][nt][r];
        }
}

extern "C" void kernel_launch(void* const* d_in, const int* in_sizes, int n_in,
                              void* d_out, int out_size, void* d_ws, size_t ws_size,
                              hipStream_t stream) {
    const float* ctx = (const float*)d_in[0];
    const float* qh = (const float*)d_in[2];
    const int* qmask = (const int*)d_in[3];
    const float* Wf = (const float*)d_in[4];
    const float* bias = (const float*)d_in[5];
    float* out = (float*)d_out;

    char* ws = (char*)d_ws;
    short* W_b     = (short*)(ws);                  //  1,179,648 B
    short* query_b = (short*)(ws + 1179648);        // 12,582,912 B
    short* qhT     = (short*)(ws + 13762560);       // 12,582,912 B
    short* ctx_b   = (short*)(ws + 26345472);       // 25,165,824 B
    short* P       = (short*)(ws + 51511296);       // 33,554,432 B -> end 85,065,728
    short* qh_b    = (short*)(ws + 51511296);       // alias with P (dead before scores writes P)

    cast_bf16_kernel<<<576, 256, 0, stream>>>(Wf, W_b, 147456);
    qh_pass_kernel<<<dim3(32, 24, 8), 256, 0, stream>>>(qh, qh_b, qhT);
    ctx_pass_kernel<<<12288, 256, 0, stream>>>(ctx, out, ctx_b);
    gemm1_kernel<<<dim3(64, 6), 256, 0, stream>>>(qh_b, W_b, bias, query_b);
    scores_fused_kernel<<<dim3(64, 8), 512, 0, stream>>>(ctx_b, query_b, qmask, P);
    gemm2_kernel<<<dim3(16, 6, 8), 256, 0, stream>>>(P, qhT, out);
}

// Round 6
// 290.268 us; speedup vs baseline: 1.0467x; 1.0467x over previous
//
#include <hip/hip_runtime.h>
#include <hip/hip_bf16.h>
#include <cstdint>
#include <cstddef>

#define D 768
#define BATCH 8
#define LC 2048
#define LQ 1024
#define SCALE 0.03608439182435161f /* 1/sqrt(768) */

typedef __attribute__((ext_vector_type(8))) short short8;
typedef __attribute__((ext_vector_type(4))) float floatx4;

__device__ __forceinline__ short f2bf(float f) {
    union { float f; uint32_t u; } v; v.f = f;
    uint32_t r = v.u + 0x7fffu + ((v.u >> 16) & 1u);
    return (short)(r >> 16);
}
__device__ __forceinline__ float bf2f(short s) {
    union { uint32_t u; float f; } v; v.u = ((uint32_t)(uint16_t)s) << 16;
    return v.f;
}

// ---- async global->LDS, 16B per lane ----
__device__ __forceinline__ void gl_lds16(const short* g, short* l) {
    __builtin_amdgcn_global_load_lds(
        reinterpret_cast<const __attribute__((address_space(1))) unsigned int*>(
            reinterpret_cast<uintptr_t>(g)),
        reinterpret_cast<__attribute__((address_space(3))) unsigned int*>(
            reinterpret_cast<uintptr_t>(l)),
        16, 0, 0);
}

// stage a 128x32 bf16 tile into lds[128][32]
__device__ __forceinline__ void stage_tile(const short* gbase, int ld, int m0, int k0,
                                           short* lds, int tid) {
    const int r = tid >> 2, kc = (tid & 3) * 8;
    gl_lds16(gbase + (size_t)(m0 + r) * ld + k0 + kc, lds + tid * 8);
    gl_lds16(gbase + (size_t)(m0 + r + 64) * ld + k0 + kc, lds + 2048 + tid * 8);
}

// m97-structure K-loop: C[128,128] += A[128,K] * B[128,K]^T
__device__ __forceinline__ void mfma_tile_loop(
    const short* Ab, const short* Bb, int lda, int ldb, int K, int m0, int n0,
    short* sA, short* sB, int tid, floatx4 acc[4][4]) {
    const int w = tid >> 6, lane = tid & 63, l15 = lane & 15, quad = lane >> 4;
    const int wm = (w >> 1) * 64, wn = (w & 1) * 64;
    for (int k0 = 0; k0 < K; k0 += 32) {
        stage_tile(Ab, lda, m0, k0, sA, tid);
        stage_tile(Bb, ldb, n0, k0, sB, tid);
        __syncthreads();
        short8 af[4], bf[4];
#pragma unroll
        for (int mt = 0; mt < 4; ++mt)
            af[mt] = *reinterpret_cast<const short8*>(&sA[(wm + mt * 16 + l15) * 32 + quad * 8]);
#pragma unroll
        for (int nt = 0; nt < 4; ++nt)
            bf[nt] = *reinterpret_cast<const short8*>(&sB[(wn + nt * 16 + l15) * 32 + quad * 8]);
#pragma unroll
        for (int mt = 0; mt < 4; ++mt)
#pragma unroll
            for (int nt = 0; nt < 4; ++nt)
                acc[mt][nt] = __builtin_amdgcn_mfma_f32_16x16x32_bf16(af[mt], bf[nt], acc[mt][nt], 0, 0, 0);
        __syncthreads();
    }
}

// ---------------- cast fp32 -> bf16 ----------------
__global__ void cast_bf16_kernel(const float* __restrict__ src, short* __restrict__ dst, int n4) {
    int i = blockIdx.x * 256 + threadIdx.x;
    if (i >= n4) return;
    float4 v = reinterpret_cast<const float4*>(src)[i];
    short4 o;
    o.x = f2bf(v.x); o.y = f2bf(v.y); o.z = f2bf(v.z); o.w = f2bf(v.w);
    reinterpret_cast<short4*>(dst)[i] = o;
}

// ---------------- qh pass: read qh once -> qh_b (bf16 row-major) + qhT (bf16 transposed) ----------------
__global__ void qh_pass_kernel(const float* __restrict__ qh, short* __restrict__ qh_b,
                               short* __restrict__ qhT) {
    __shared__ float tile[32][33];
    const int b = blockIdx.z;
    const int q0 = blockIdx.x * 32, d0 = blockIdx.y * 32;
    const int t = threadIdx.x;
    const int r = t >> 3, c = (t & 7) * 4;
    const float4 v = *reinterpret_cast<const float4*>(qh + ((size_t)b * LQ + q0 + r) * D + d0 + c);
    tile[r][c] = v.x; tile[r][c + 1] = v.y; tile[r][c + 2] = v.z; tile[r][c + 3] = v.w;
    short4 d;
    d.x = f2bf(v.x); d.y = f2bf(v.y); d.z = f2bf(v.z); d.w = f2bf(v.w);
    *reinterpret_cast<short4*>(qh_b + ((size_t)b * LQ + q0 + r) * D + d0 + c) = d;
    __syncthreads();
    short4 o;
    o.x = f2bf(tile[c][r]); o.y = f2bf(tile[c + 1][r]);
    o.z = f2bf(tile[c + 2][r]); o.w = f2bf(tile[c + 3][r]);
    *reinterpret_cast<short4*>(qhT + ((size_t)b * D + d0 + r) * LQ + q0 + c) = o;
}

// ---------------- GEMM1: query = qh_b * W_b^T + bias -> bf16 ----------------
__global__ __launch_bounds__(256, 2) void gemm1_kernel(
    const short* __restrict__ A, const short* __restrict__ W,
    const float* __restrict__ bias, short* __restrict__ Q) {
    __shared__ short sA[128 * 32];
    __shared__ short sB[128 * 32];
    const int m0 = blockIdx.x * 128, n0 = blockIdx.y * 128;
    const int tid = threadIdx.x;
    const int w = tid >> 6, lane = tid & 63, l15 = lane & 15, quad = lane >> 4;
    const int wm = (w >> 1) * 64, wn = (w & 1) * 64;
    floatx4 acc[4][4];
#pragma unroll
    for (int i = 0; i < 4; ++i)
#pragma unroll
        for (int j = 0; j < 4; ++j) { floatx4 z = {0.f, 0.f, 0.f, 0.f}; acc[i][j] = z; }
    mfma_tile_loop(A, W, D, D, D, m0, n0, sA, sB, tid, acc);
    float bv[4];
#pragma unroll
    for (int nt = 0; nt < 4; ++nt) bv[nt] = bias[n0 + wn + nt * 16 + l15];
#pragma unroll
    for (int mt = 0; mt < 4; ++mt)
#pragma unroll
        for (int r = 0; r < 4; ++r) {
            int row = m0 + wm + mt * 16 + quad * 4 + r;
#pragma unroll
            for (int nt = 0; nt < 4; ++nt)
                Q[(size_t)row * D + n0 + wn + nt * 16 + l15] = f2bf(acc[mt][nt][r] + bv[nt]);
        }
}

// ---------------- ctx pass: copy ctx into out[:, :, 0:768] AND cast to bf16 ----------------
__global__ void ctx_pass_kernel(const float* __restrict__ ctx, float* __restrict__ out,
                                short* __restrict__ ctxb) {
    size_t i = (size_t)blockIdx.x * 256 + threadIdx.x;
    size_t row = i / 192;
    size_t c4 = i % 192;
    float4 v = reinterpret_cast<const float4*>(ctx)[i];
    reinterpret_cast<float4*>(out)[row * 384 + c4] = v;
    short4 o;
    o.x = f2bf(v.x); o.y = f2bf(v.y); o.z = f2bf(v.z); o.w = f2bf(v.w);
    reinterpret_cast<short4*>(ctxb)[i] = o;
}

// ---------------- K1: raw scores S = ctx_b * query_b^T -> bf16 ----------------
__global__ __launch_bounds__(256, 2) void scores_gemm_kernel(
    const short* __restrict__ ctxb, const short* __restrict__ query_b,
    short* __restrict__ S) {
    __shared__ short sA[128 * 32];
    __shared__ short sB[128 * 32];
    const int b = blockIdx.z;
    const int m0 = blockIdx.x * 128, n0 = blockIdx.y * 128;
    const int tid = threadIdx.x;
    const int w = tid >> 6, lane = tid & 63, l15 = lane & 15, quad = lane >> 4;
    const int wm = (w >> 1) * 64, wn = (w & 1) * 64;
    floatx4 acc[4][4];
#pragma unroll
    for (int i = 0; i < 4; ++i)
#pragma unroll
        for (int j = 0; j < 4; ++j) { floatx4 z = {0.f, 0.f, 0.f, 0.f}; acc[i][j] = z; }
    mfma_tile_loop(ctxb + (size_t)b * LC * D, query_b + (size_t)b * LQ * D,
                   D, D, D, m0, n0, sA, sB, tid, acc);
    short* Sb = S + (size_t)b * LC * LQ;
#pragma unroll
    for (int mt = 0; mt < 4; ++mt)
#pragma unroll
        for (int r = 0; r < 4; ++r) {
            size_t row = m0 + wm + mt * 16 + quad * 4 + r;
#pragma unroll
            for (int nt = 0; nt < 4; ++nt)
                Sb[row * LQ + n0 + wn + nt * 16 + l15] = f2bf(acc[mt][nt][r]);
        }
}

// ---------------- softmax in place on S bf16 (scale+mask applied here) ----------------
__global__ __launch_bounds__(256) void softmax_kernel(short* __restrict__ S,
                                                      const int* __restrict__ qmask) {
    __shared__ float redM[4], redS[4];
    const int row = blockIdx.x;              // 0..16383
    const int b = row >> 11;
    const int t = threadIdx.x;
    const int wv = t >> 6, lane = t & 63;
    short* srow = S + (size_t)row * LQ;
    short4 v = reinterpret_cast<short4*>(srow)[t];
    int4 m4 = reinterpret_cast<const int4*>(qmask + (size_t)b * LQ)[t];
    float x0 = m4.x ? bf2f(v.x) * SCALE : -1e30f;
    float x1 = m4.y ? bf2f(v.y) * SCALE : -1e30f;
    float x2 = m4.z ? bf2f(v.z) * SCALE : -1e30f;
    float x3 = m4.w ? bf2f(v.w) * SCALE : -1e30f;
    float m = fmaxf(fmaxf(x0, x1), fmaxf(x2, x3));
#pragma unroll
    for (int off = 1; off < 64; off <<= 1) m = fmaxf(m, __shfl_xor(m, off, 64));
    if (lane == 0) redM[wv] = m;
    __syncthreads();
    m = fmaxf(fmaxf(redM[0], redM[1]), fmaxf(redM[2], redM[3]));
    float p0 = __expf(x0 - m), p1 = __expf(x1 - m), p2 = __expf(x2 - m), p3 = __expf(x3 - m);
    float s = p0 + p1 + p2 + p3;
#pragma unroll
    for (int off = 1; off < 64; off <<= 1) s += __shfl_xor(s, off, 64);
    if (lane == 0) redS[wv] = s;
    __syncthreads();
    s = redS[0] + redS[1] + redS[2] + redS[3];
    const float inv = 1.0f / s;
    short4 o;
    o.x = f2bf(p0 * inv); o.y = f2bf(p1 * inv); o.z = f2bf(p2 * inv); o.w = f2bf(p3 * inv);
    reinterpret_cast<short4*>(srow)[t] = o;
}

// ---------------- K2: attn_out = P * qhT^T -> fp32 into out[...,768:] ----------------
__global__ __launch_bounds__(256, 2) void gemm2_kernel(
    const short* __restrict__ P, const short* __restrict__ qhT,
    float* __restrict__ out) {
    __shared__ short sA[128 * 32];
    __shared__ short sB[128 * 32];
    const int b = blockIdx.z;
    const int m0 = blockIdx.x * 128, n0 = blockIdx.y * 128;
    const int tid = threadIdx.x;
    const int w = tid >> 6, lane = tid & 63, l15 = lane & 15, quad = lane >> 4;
    const int wm = (w >> 1) * 64, wn = (w & 1) * 64;
    floatx4 acc[4][4];
#pragma unroll
    for (int i = 0; i < 4; ++i)
#pragma unroll
        for (int j = 0; j < 4; ++j) { floatx4 z = {0.f, 0.f, 0.f, 0.f}; acc[i][j] = z; }
    mfma_tile_loop(P + (size_t)b * LC * LQ, qhT + (size_t)b * D * LQ,
                   LQ, LQ, LQ, m0, n0, sA, sB, tid, acc);
#pragma unroll
    for (int mt = 0; mt < 4; ++mt)
#pragma unroll
        for (int r = 0; r < 4; ++r) {
            size_t row = (size_t)b * LC + m0 + wm + mt * 16 + quad * 4 + r;
#pragma unroll
            for (int nt = 0; nt < 4; ++nt)
                out[row * 1536 + 768 + n0 + wn + nt * 16 + l15] = acc[mt][nt][r];
        }
}

extern "C" void kernel_launch(void* const* d_in, const int* in_sizes, int n_in,
                              void* d_out, int out_size, void* d_ws, size_t ws_size,
                              hipStream_t stream) {
    const float* ctx = (const float*)d_in[0];
    const float* qh = (const float*)d_in[2];
    const int* qmask = (const int*)d_in[3];
    const float* Wf = (const float*)d_in[4];
    const float* bias = (const float*)d_in[5];
    float* out = (float*)d_out;

    char* ws = (char*)d_ws;
    short* W_b     = (short*)(ws);                  //  1,179,648 B
    short* query_b = (short*)(ws + 1179648);        // 12,582,912 B
    short* qhT     = (short*)(ws + 13762560);       // 12,582,912 B
    short* ctx_b   = (short*)(ws + 26345472);       // 25,165,824 B
    short* S       = (short*)(ws + 51511296);       // 33,554,432 B -> end 85,065,728
    short* qh_b    = (short*)(ws + 51511296);       // alias with S (dead before scores writes S)

    cast_bf16_kernel<<<576, 256, 0, stream>>>(Wf, W_b, 147456);
    qh_pass_kernel<<<dim3(32, 24, 8), 256, 0, stream>>>(qh, qh_b, qhT);
    ctx_pass_kernel<<<12288, 256, 0, stream>>>(ctx, out, ctx_b);
    gemm1_kernel<<<dim3(64, 6), 256, 0, stream>>>(qh_b, W_b, bias, query_b);
    scores_gemm_kernel<<<dim3(16, 8, 8), 256, 0, stream>>>(ctx_b, query_b, S);
    softmax_kernel<<<16384, 256, 0, stream>>>(S, qmask);
    gemm2_kernel<<<dim3(16, 6, 8), 256, 0, stream>>>(S, qhT, out);
}

// Round 7
// 272.906 us; speedup vs baseline: 1.1133x; 1.0636x over previous
//
#include <hip/hip_runtime.h>
#include <hip/hip_bf16.h>
#include <cstdint>
#include <cstddef>

#define D 768
#define BATCH 8
#define LC 2048
#define LQ 1024
#define SCALE 0.03608439182435161f /* 1/sqrt(768) */

typedef __attribute__((ext_vector_type(8))) short short8;
typedef __attribute__((ext_vector_type(4))) float floatx4;

__device__ __forceinline__ short f2bf(float f) {
    union { float f; uint32_t u; } v; v.f = f;
    uint32_t r = v.u + 0x7fffu + ((v.u >> 16) & 1u);
    return (short)(r >> 16);
}

// ---- async global->LDS, 16B per lane ----
__device__ __forceinline__ void gl_lds16(const short* g, short* l) {
    __builtin_amdgcn_global_load_lds(
        reinterpret_cast<const __attribute__((address_space(1))) unsigned int*>(
            reinterpret_cast<uintptr_t>(g)),
        reinterpret_cast<__attribute__((address_space(3))) unsigned int*>(
            reinterpret_cast<uintptr_t>(l)),
        16, 0, 0);
}

// stage a 128x32 bf16 tile into lds[128][32]
__device__ __forceinline__ void stage_tile(const short* gbase, int ld, int m0, int k0,
                                           short* lds, int tid) {
    const int r = tid >> 2, kc = (tid & 3) * 8;
    gl_lds16(gbase + (size_t)(m0 + r) * ld + k0 + kc, lds + tid * 8);
    gl_lds16(gbase + (size_t)(m0 + r + 64) * ld + k0 + kc, lds + 2048 + tid * 8);
}

// m97-structure K-loop: C[128,128] += A[128,K] * B[128,K]^T
__device__ __forceinline__ void mfma_tile_loop(
    const short* Ab, const short* Bb, int lda, int ldb, int K, int m0, int n0,
    short* sA, short* sB, int tid, floatx4 acc[4][4]) {
    const int w = tid >> 6, lane = tid & 63, l15 = lane & 15, quad = lane >> 4;
    const int wm = (w >> 1) * 64, wn = (w & 1) * 64;
    for (int k0 = 0; k0 < K; k0 += 32) {
        stage_tile(Ab, lda, m0, k0, sA, tid);
        stage_tile(Bb, ldb, n0, k0, sB, tid);
        __syncthreads();
        short8 af[4], bf[4];
#pragma unroll
        for (int mt = 0; mt < 4; ++mt)
            af[mt] = *reinterpret_cast<const short8*>(&sA[(wm + mt * 16 + l15) * 32 + quad * 8]);
#pragma unroll
        for (int nt = 0; nt < 4; ++nt)
            bf[nt] = *reinterpret_cast<const short8*>(&sB[(wn + nt * 16 + l15) * 32 + quad * 8]);
#pragma unroll
        for (int mt = 0; mt < 4; ++mt)
#pragma unroll
            for (int nt = 0; nt < 4; ++nt)
                acc[mt][nt] = __builtin_amdgcn_mfma_f32_16x16x32_bf16(af[mt], bf[nt], acc[mt][nt], 0, 0, 0);
        __syncthreads();
    }
}

// ---------------- cast W fp32 -> bf16, and zero the row-sum buffer ----------------
__global__ void cast_w_kernel(const float* __restrict__ src, short* __restrict__ dst,
                              float* __restrict__ sums) {
    int i = blockIdx.x * 256 + threadIdx.x;
    if (i < 4096) {  // zero 16384 floats (row sums) with first 16 blocks' worth of lanes
        float4 z = {0.f, 0.f, 0.f, 0.f};
        reinterpret_cast<float4*>(sums)[i] = z;
    }
    float4 v = reinterpret_cast<const float4*>(src)[i];
    short4 o;
    o.x = f2bf(v.x); o.y = f2bf(v.y); o.z = f2bf(v.z); o.w = f2bf(v.w);
    reinterpret_cast<short4*>(dst)[i] = o;
}

// ---------------- qh pass: read qh once -> qh_b (bf16 row-major) + qhT (bf16 transposed) ----------------
__global__ void qh_pass_kernel(const float* __restrict__ qh, short* __restrict__ qh_b,
                               short* __restrict__ qhT) {
    __shared__ float tile[32][33];
    const int b = blockIdx.z;
    const int q0 = blockIdx.x * 32, d0 = blockIdx.y * 32;
    const int t = threadIdx.x;
    const int r = t >> 3, c = (t & 7) * 4;
    const float4 v = *reinterpret_cast<const float4*>(qh + ((size_t)b * LQ + q0 + r) * D + d0 + c);
    tile[r][c] = v.x; tile[r][c + 1] = v.y; tile[r][c + 2] = v.z; tile[r][c + 3] = v.w;
    short4 d;
    d.x = f2bf(v.x); d.y = f2bf(v.y); d.z = f2bf(v.z); d.w = f2bf(v.w);
    *reinterpret_cast<short4*>(qh_b + ((size_t)b * LQ + q0 + r) * D + d0 + c) = d;
    __syncthreads();
    short4 o;
    o.x = f2bf(tile[c][r]); o.y = f2bf(tile[c + 1][r]);
    o.z = f2bf(tile[c + 2][r]); o.w = f2bf(tile[c + 3][r]);
    *reinterpret_cast<short4*>(qhT + ((size_t)b * D + d0 + r) * LQ + q0 + c) = o;
}

// ---------------- GEMM1: query = qh_b * W_b^T + bias -> bf16 ----------------
__global__ __launch_bounds__(256, 2) void gemm1_kernel(
    const short* __restrict__ A, const short* __restrict__ W,
    const float* __restrict__ bias, short* __restrict__ Q) {
    __shared__ short sA[128 * 32];
    __shared__ short sB[128 * 32];
    const int m0 = blockIdx.x * 128, n0 = blockIdx.y * 128;
    const int tid = threadIdx.x;
    const int w = tid >> 6, lane = tid & 63, l15 = lane & 15, quad = lane >> 4;
    const int wm = (w >> 1) * 64, wn = (w & 1) * 64;
    floatx4 acc[4][4];
#pragma unroll
    for (int i = 0; i < 4; ++i)
#pragma unroll
        for (int j = 0; j < 4; ++j) { floatx4 z = {0.f, 0.f, 0.f, 0.f}; acc[i][j] = z; }
    mfma_tile_loop(A, W, D, D, D, m0, n0, sA, sB, tid, acc);
    float bv[4];
#pragma unroll
    for (int nt = 0; nt < 4; ++nt) bv[nt] = bias[n0 + wn + nt * 16 + l15];
#pragma unroll
    for (int mt = 0; mt < 4; ++mt)
#pragma unroll
        for (int r = 0; r < 4; ++r) {
            int row = m0 + wm + mt * 16 + quad * 4 + r;
#pragma unroll
            for (int nt = 0; nt < 4; ++nt)
                Q[(size_t)row * D + n0 + wn + nt * 16 + l15] = f2bf(acc[mt][nt][r] + bv[nt]);
        }
}

// ---------------- ctx pass: copy ctx into out[:, :, 0:768] AND cast to bf16 ----------------
__global__ void ctx_pass_kernel(const float* __restrict__ ctx, float* __restrict__ out,
                                short* __restrict__ ctxb) {
    size_t i = (size_t)blockIdx.x * 256 + threadIdx.x;
    size_t row = i / 192;
    size_t c4 = i % 192;
    float4 v = reinterpret_cast<const float4*>(ctx)[i];
    reinterpret_cast<float4*>(out)[row * 384 + c4] = v;
    short4 o;
    o.x = f2bf(v.x); o.y = f2bf(v.y); o.z = f2bf(v.z); o.w = f2bf(v.w);
    reinterpret_cast<short4*>(ctxb)[i] = o;
}

// ---------------- K1: P_unnorm = mask ? exp(scale * ctx_b*query_b^T) : 0  (bf16)
//                  + fp32 row-sum accumulation via atomics ----------------
__global__ __launch_bounds__(256, 2) void scores_gemm_kernel(
    const short* __restrict__ ctxb, const short* __restrict__ query_b,
    const int* __restrict__ qmask, short* __restrict__ P, float* __restrict__ sums) {
    __shared__ short sA[128 * 32];
    __shared__ short sB[128 * 32];
    const int b = blockIdx.z;
    const int m0 = blockIdx.x * 128, n0 = blockIdx.y * 128;
    const int tid = threadIdx.x;
    const int w = tid >> 6, lane = tid & 63, l15 = lane & 15, quad = lane >> 4;
    const int wm = (w >> 1) * 64, wn = (w & 1) * 64;
    floatx4 acc[4][4];
#pragma unroll
    for (int i = 0; i < 4; ++i)
#pragma unroll
        for (int j = 0; j < 4; ++j) { floatx4 z = {0.f, 0.f, 0.f, 0.f}; acc[i][j] = z; }
    mfma_tile_loop(ctxb + (size_t)b * LC * D, query_b + (size_t)b * LQ * D,
                   D, D, D, m0, n0, sA, sB, tid, acc);
    const int* mk = qmask + b * LQ;
    bool valid[4];
#pragma unroll
    for (int nt = 0; nt < 4; ++nt) valid[nt] = (mk[n0 + wn + nt * 16 + l15] != 0);
    short* Pb = P + (size_t)b * LC * LQ;
    float* sumb = sums + b * LC;
#pragma unroll
    for (int mt = 0; mt < 4; ++mt)
#pragma unroll
        for (int r = 0; r < 4; ++r) {
            size_t row = m0 + wm + mt * 16 + quad * 4 + r;
            float psum = 0.f;
#pragma unroll
            for (int nt = 0; nt < 4; ++nt) {
                float pv = valid[nt] ? __expf(acc[mt][nt][r] * SCALE) : 0.f;
                psum += pv;
                Pb[row * LQ + n0 + wn + nt * 16 + l15] = f2bf(pv);
            }
            // reduce psum across the 16 l15 lanes of this quad
#pragma unroll
            for (int off = 1; off < 16; off <<= 1)
                psum += __shfl_xor(psum, off, 64);
            if (l15 == 0)
                atomicAdd(&sumb[row], psum);
        }
}

// ---------------- K2: attn_out = (P_unnorm * qhT^T) / rowsum -> fp32 into out[...,768:] ----------------
__global__ __launch_bounds__(256, 2) void gemm2_kernel(
    const short* __restrict__ P, const short* __restrict__ qhT,
    const float* __restrict__ sums, float* __restrict__ out) {
    __shared__ short sA[128 * 32];
    __shared__ short sB[128 * 32];
    const int b = blockIdx.z;
    const int m0 = blockIdx.x * 128, n0 = blockIdx.y * 128;
    const int tid = threadIdx.x;
    const int w = tid >> 6, lane = tid & 63, l15 = lane & 15, quad = lane >> 4;
    const int wm = (w >> 1) * 64, wn = (w & 1) * 64;
    floatx4 acc[4][4];
#pragma unroll
    for (int i = 0; i < 4; ++i)
#pragma unroll
        for (int j = 0; j < 4; ++j) { floatx4 z = {0.f, 0.f, 0.f, 0.f}; acc[i][j] = z; }
    mfma_tile_loop(P + (size_t)b * LC * LQ, qhT + (size_t)b * D * LQ,
                   LQ, LQ, LQ, m0, n0, sA, sB, tid, acc);
    const float* sumb = sums + b * LC;
#pragma unroll
    for (int mt = 0; mt < 4; ++mt)
#pragma unroll
        for (int r = 0; r < 4; ++r) {
            int lrow = m0 + wm + mt * 16 + quad * 4 + r;
            const float inv = 1.0f / sumb[lrow];
            size_t row = (size_t)b * LC + lrow;
#pragma unroll
            for (int nt = 0; nt < 4; ++nt)
                out[row * 1536 + 768 + n0 + wn + nt * 16 + l15] = acc[mt][nt][r] * inv;
        }
}

extern "C" void kernel_launch(void* const* d_in, const int* in_sizes, int n_in,
                              void* d_out, int out_size, void* d_ws, size_t ws_size,
                              hipStream_t stream) {
    const float* ctx = (const float*)d_in[0];
    const float* qh = (const float*)d_in[2];
    const int* qmask = (const int*)d_in[3];
    const float* Wf = (const float*)d_in[4];
    const float* bias = (const float*)d_in[5];
    float* out = (float*)d_out;

    char* ws = (char*)d_ws;
    short* W_b     = (short*)(ws);                  //  1,179,648 B
    short* query_b = (short*)(ws + 1179648);        // 12,582,912 B
    short* qhT     = (short*)(ws + 13762560);       // 12,582,912 B
    short* ctx_b   = (short*)(ws + 26345472);       // 25,165,824 B
    short* P       = (short*)(ws + 51511296);       // 33,554,432 B
    float* sums    = (float*)(ws + 85065728);       //     65,536 B -> end 85,131,264
    short* qh_b    = (short*)(ws + 51511296);       // alias with P (dead before scores writes P)

    cast_w_kernel<<<576, 256, 0, stream>>>(Wf, W_b, sums);
    qh_pass_kernel<<<dim3(32, 24, 8), 256, 0, stream>>>(qh, qh_b, qhT);
    ctx_pass_kernel<<<12288, 256, 0, stream>>>(ctx, out, ctx_b);
    gemm1_kernel<<<dim3(64, 6), 256, 0, stream>>>(qh_b, W_b, bias, query_b);
    scores_gemm_kernel<<<dim3(16, 8, 8), 256, 0, stream>>>(ctx_b, query_b, qmask, P, sums);
    gemm2_kernel<<<dim3(16, 6, 8), 256, 0, stream>>>(P, qhT, sums, out);
}